// Round 6
// baseline (161.181 us; speedup 1.0000x reference)
//
#include <hip/hip_runtime.h>
#include <stdint.h>
#include <stddef.h>

// ---------------------------------------------------------------------------
// out = softmax(x Wq+bq @ (x Wk+bk)^T) * sqrt(512) @ (x Wv+bv)
// B=8, N=2048, D=DK=DV=512, fp32 I/O.
// Round 6: round-5 pipeline with the compile fix: __exp2f -> 
// __builtin_amdgcn_exp2f (v_exp_f32 computes 2^x). k_pv3 = S reg-prefetch
// 1 iter ahead, counted s_waitcnt vmcnt(4) at the staging barrier (S loads
// stay in flight across the MFMA phase), lgkmcnt-only top barrier.
// conv/proj/qk unchanged.
// ws layout (B): x16 0, Q 16777216, K 33554432, Vt 50331648,
//   S 67108864 (134217728), Wt 201326592 (1572864), mEnc 202899456 (65536).
//   total 202964992.
// ---------------------------------------------------------------------------

typedef _Float16 f16_t;
typedef _Float16 f16x8 __attribute__((ext_vector_type(8)));
typedef float    f32x4 __attribute__((ext_vector_type(4)));

__device__ __forceinline__ f32x4 mfma_h(f16x8 a, f16x8 b, f32x4 c) {
  // D frag: col = lane&15, row = (lane>>4)*4 + reg
  return __builtin_amdgcn_mfma_f32_16x16x32_f16(a, b, c, 0, 0, 0);
}

__device__ __forceinline__ void gl_lds16(const void* g, void* lds) {
  __builtin_amdgcn_global_load_lds(
      (const __attribute__((address_space(1))) unsigned int*)g,
      (__attribute__((address_space(3))) unsigned int*)lds, 16, 0, 0);
}

// Stage a [128][64] f16 tile (16 KB) from row-major global via global_load_lds.
// Linear LDS dest; source pre-swizzled: phys slot s of row r holds logical
// slot s^(r&7) (16B slots, 8 per 128B row).  4-wave cooperative.
__device__ __forceinline__ void stage_tile(f16_t* lds, const f16_t* g,
                                           size_t gstride, int wave, int lane) {
  const int l8 = lane >> 3;
  const int lslot = (lane & 7) ^ l8;
  #pragma unroll
  for (int c = 0; c < 4; ++c) {
    const int chunk = wave * 4 + c;
    const int row = chunk * 8 + l8;
    gl_lds16(g + (size_t)row * gstride + lslot * 8, lds + chunk * 512);
  }
}

// Swizzled fragment read: logical (row R, 8 elems at col slot*8)
__device__ __forceinline__ f16x8 lds_frag(const f16_t* buf, int R, int slot) {
  return *(const f16x8*)&buf[R * 64 + (((slot ^ (R & 7)) & 7) << 3)];
}

// monotonic float<->uint encoding for atomicMax (memset-0 == -huge sentinel)
__device__ __forceinline__ unsigned int fenc(float f) {
  unsigned int u = __float_as_uint(f);
  return (u & 0x80000000u) ? ~u : (u | 0x80000000u);
}
__device__ __forceinline__ float fdec(unsigned int e) {
  unsigned int u = (e & 0x80000000u) ? (e & 0x7fffffffu) : ~e;
  return __uint_as_float(u);
}

// XCD-chunked work remap (requires nwg % 8 == 0)
__device__ __forceinline__ int xcd_swz(int id, int nwg) {
  return (id & 7) * (nwg >> 3) + (id >> 3);
}

// ---------------------------------------------------------------------------
__global__ __launch_bounds__(256) void k_conv_x(const float* __restrict__ x,
                                                f16_t* __restrict__ x16) {
  const int i = (blockIdx.x * 256 + threadIdx.x) * 8;
  const float4 a = *(const float4*)&x[i];
  const float4 b = *(const float4*)&x[i + 4];
  float v[8] = {a.x, a.y, a.z, a.w, b.x, b.y, b.z, b.w};
  f16x8 h;
  #pragma unroll
  for (int j = 0; j < 8; ++j) h[j] = (f16_t)v[j];
  *(f16x8*)&x16[i] = h;
}

// transpose+convert W -> Wt[p][n][k] f16
__global__ __launch_bounds__(256) void k_conv_w(const float* __restrict__ Wq,
                                                const float* __restrict__ Wk,
                                                const float* __restrict__ Wv,
                                                f16_t* __restrict__ Wt) {
  __shared__ float t[64][65];
  const int p = blockIdx.z;
  const float* __restrict__ W = (p == 0) ? Wq : (p == 1) ? Wk : Wv;
  const int n0 = blockIdx.x * 64, k0 = blockIdx.y * 64;
  const int tx = threadIdx.x & 63, ty = threadIdx.x >> 6;
  #pragma unroll
  for (int j = 0; j < 16; ++j)
    t[ty * 16 + j][tx] = W[(size_t)(k0 + ty * 16 + j) * 512 + n0 + tx];
  __syncthreads();
  #pragma unroll
  for (int j = 0; j < 16; ++j) {
    const int nl = ty * 16 + j;
    Wt[(size_t)p * 262144 + (size_t)(n0 + nl) * 512 + k0 + tx] =
        (f16_t)t[tx][nl];
  }
}

// ---------------------------------------------------------------------------
// Projection: flat grid 1536 (xcd-swizzled -> mt*12+jt).  Single fp16 MFMA.
// panels 0-3 Q, 4-7 K, 8-11 V (V transposed to Vt[b][dv][n]).
// ---------------------------------------------------------------------------
__global__ __launch_bounds__(256, 2) void k_proj(
    const f16_t* __restrict__ x16, const f16_t* __restrict__ Wt,
    const float* __restrict__ bq, const float* __restrict__ bk,
    const float* __restrict__ bv,
    f16_t* __restrict__ Q, f16_t* __restrict__ K, f16_t* __restrict__ Vt)
{
  __shared__ __align__(16) unsigned char smem[34816];  // A,B tiles / vtl
  f16_t* A = (f16_t*)smem;
  f16_t* B = (f16_t*)(smem + 16384);

  const int wg = xcd_swz(blockIdx.x, 1536);
  const int mt = wg / 12, jt = wg % 12;
  const int which = jt >> 2;            // 0=Q 1=K 2=V
  const int jb = (jt & 3) * 128;

  const int tid = threadIdx.x, lane = tid & 63, wave = tid >> 6;
  const int wr = wave >> 1, wc = wave & 1, l15 = lane & 15, lg = lane >> 4;
  const int rowbase = mt * 128;

  const f16_t* Wbase = Wt + (size_t)which * 262144 + (size_t)jb * 512;

  f32x4 acc[4][4] = {};

  for (int kb = 0; kb < 512; kb += 64) {
    __syncthreads();
    stage_tile(A, x16 + (size_t)rowbase * 512 + kb, 512, wave, lane);
    stage_tile(B, Wbase + kb, 512, wave, lane);
    __syncthreads();
    #pragma unroll
    for (int h = 0; h < 2; ++h) {
      const int slot0 = h * 4 + lg;
      f16x8 af[4], bf[4];
      #pragma unroll
      for (int g = 0; g < 4; ++g) {
        af[g] = lds_frag(A, wr * 64 + g * 16 + l15, slot0);
        bf[g] = lds_frag(B, wc * 64 + g * 16 + l15, slot0);
      }
      #pragma unroll
      for (int i = 0; i < 4; ++i)
        #pragma unroll
        for (int j = 0; j < 4; ++j)
          acc[i][j] = mfma_h(af[i], bf[j], acc[i][j]);
    }
  }

  if (which != 2) {
    f16_t* __restrict__ O = (which == 0) ? Q : K;
    const float* __restrict__ bb = (which == 0) ? bq : bk;
    #pragma unroll
    for (int j = 0; j < 4; ++j) {
      const int jl = jb + wc * 64 + j * 16 + l15;
      const float bias = bb[jl];
      #pragma unroll
      for (int i = 0; i < 4; ++i)
        #pragma unroll
        for (int r = 0; r < 4; ++r) {
          const int row = rowbase + wr * 64 + i * 16 + lg * 4 + r;
          O[(size_t)row * 512 + jl] = (f16_t)(acc[i][j][r] + bias);
        }
    }
  } else {
    __syncthreads();
    f16_t* vtl = (f16_t*)smem;          // [128][136] f16 = 34816 B
    #pragma unroll
    for (int j = 0; j < 4; ++j) {
      const int jj = wc * 64 + j * 16 + l15;
      const float bias = bv[jb + jj];
      #pragma unroll
      for (int i = 0; i < 4; ++i)
        #pragma unroll
        for (int r = 0; r < 4; ++r) {
          const int ii = wr * 64 + i * 16 + lg * 4 + r;
          vtl[jj * 136 + ii] = (f16_t)(acc[i][j][r] + bias);
        }
    }
    __syncthreads();
    const int dv = tid >> 1, hf = tid & 1;
    const int bat = rowbase >> 11, n0 = rowbase & 2047;
    f16_t* __restrict__ dst =
        &Vt[((size_t)bat * 512 + jb + dv) * 2048 + n0 + hf * 64];
    const f16_t* src = &vtl[dv * 136 + hf * 64];
    #pragma unroll
    for (int s = 0; s < 8; ++s)
      *(f16x8*)&dst[s * 8] = *(const f16x8*)&src[s * 8];
  }
}

// ---------------------------------------------------------------------------
// S = Q K^T (fp32 out) + encoded row-max atomics.  flat grid 2048.
// decode: bat = wg>>8 (one batch per XCD), mt = (wg>>4)&15, nt = wg&15.
// ---------------------------------------------------------------------------
__global__ __launch_bounds__(256, 2) void k_qk(const f16_t* __restrict__ Q,
                                               const f16_t* __restrict__ K,
                                               float* __restrict__ S,
                                               unsigned int* __restrict__ mEnc)
{
  __shared__ __align__(16) f16_t A[128 * 64];
  __shared__ __align__(16) f16_t Bt[128 * 64];

  const int wg = xcd_swz(blockIdx.x, 2048);
  const int bat = wg >> 8, mt = (wg >> 4) & 15, nt = wg & 15;
  const int tid = threadIdx.x, lane = tid & 63, wave = tid >> 6;
  const int wr = wave >> 1, wc = wave & 1, l15 = lane & 15, lg = lane >> 4;

  f32x4 acc[4][4] = {};
  const f16_t* Abase = Q + ((size_t)bat * 2048 + mt * 128) * 512;
  const f16_t* Bbase = K + ((size_t)bat * 2048 + nt * 128) * 512;

  for (int kb = 0; kb < 512; kb += 64) {
    __syncthreads();
    stage_tile(A, Abase + kb, 512, wave, lane);
    stage_tile(Bt, Bbase + kb, 512, wave, lane);
    __syncthreads();
    #pragma unroll
    for (int h = 0; h < 2; ++h) {
      const int slot0 = h * 4 + lg;
      f16x8 af[4], bf[4];
      #pragma unroll
      for (int g = 0; g < 4; ++g) {
        af[g] = lds_frag(A, wr * 64 + g * 16 + l15, slot0);
        bf[g] = lds_frag(Bt, wc * 64 + g * 16 + l15, slot0);
      }
      #pragma unroll
      for (int i = 0; i < 4; ++i)
        #pragma unroll
        for (int j = 0; j < 4; ++j)
          acc[i][j] = mfma_h(af[i], bf[j], acc[i][j]);
    }
  }

  #pragma unroll
  for (int i = 0; i < 4; ++i)
    #pragma unroll
    for (int r = 0; r < 4; ++r) {
      const int ii = mt * 128 + wr * 64 + i * 16 + lg * 4 + r;
      float mv = fmaxf(fmaxf(acc[i][0][r], acc[i][1][r]),
                       fmaxf(acc[i][2][r], acc[i][3][r]));
      mv = fmaxf(mv, __shfl_xor(mv, 1));
      mv = fmaxf(mv, __shfl_xor(mv, 2));
      mv = fmaxf(mv, __shfl_xor(mv, 4));
      mv = fmaxf(mv, __shfl_xor(mv, 8));
      if (l15 == 0)
        atomicMax(&mEnc[(size_t)bat * 2048 + ii], fenc(mv));
      #pragma unroll
      for (int j = 0; j < 4; ++j) {
        const int jj = nt * 128 + wc * 64 + j * 16 + l15;
        S[((size_t)bat * 2048 + ii) * 2048 + jj] = acc[i][j][r];
      }
    }
}

// ---------------------------------------------------------------------------
// out = (exp(S - m) @ V) * sqrt(512)/l.  flat grid 512 = bat(8, =XCD) x
// qt(32 tiles of 64 q) x dvh(2 halves of 256 dv).  4 waves, each 64q x 64dv.
// Pipelined: S reg-prefetch 1 iter ahead; staging barrier is counted
// (vmcnt(4): drain 8 V gl_lds, keep 4 S loads in flight); top barrier
// drains lgkmcnt only.  Phase order pinned with sched_barrier(0).
// ---------------------------------------------------------------------------
__global__ __launch_bounds__(256, 2) void k_pv3(const float* __restrict__ S,
                                                const f16_t* __restrict__ Vt,
                                                const unsigned int* __restrict__ mEnc,
                                                float* __restrict__ out)
{
  __shared__ __align__(16) f16_t P[64 * 64];      // [q][kv] swizzled, 8 KB
  __shared__ __align__(16) f16_t Vl[256 * 64];    // [dv][kv] swizzled, 32 KB
  __shared__ float lred[64][4];

  const int id = blockIdx.x;
  const int bat = id & 7, qt = (id >> 3) & 31, dvh = id >> 8;
  const int tid = threadIdx.x, lane = tid & 63, wave = tid >> 6;
  const int l15 = lane & 15, lg = lane >> 4;

  const int qs = tid >> 2;           // staging q row 0..63
  const int cq = tid & 3;            // quarter of the 64-kv step
  const float LOG2E = 1.4426950408889634f;
  const float mls = fdec(mEnc[bat * 2048 + qt * 64 + qs]) * LOG2E;
  const float* __restrict__ srow =
      S + ((size_t)bat * 2048 + qt * 64 + qs) * 2048;
  const f16_t* Vbase = Vt + ((size_t)bat * 512 + dvh * 256) * 2048;

  f32x4 acc[4][4] = {};
  float l_part = 0.f;

  // prologue: prefetch S for kb=0
  float4 s0 = *(const float4*)&srow[cq * 16];
  float4 s1 = *(const float4*)&srow[cq * 16 + 4];
  float4 s2 = *(const float4*)&srow[cq * 16 + 8];
  float4 s3 = *(const float4*)&srow[cq * 16 + 12];

  for (int kb = 0; kb < 2048; kb += 64) {
    // (A) top barrier: prev MFMA reads all consumed (lgkmcnt only; S loads
    // from the previous staging phase stay in flight).
    asm volatile("s_waitcnt lgkmcnt(0)\n\ts_barrier" ::: "memory");
    __builtin_amdgcn_sched_barrier(0);
    // phase 1a: V stage -- 8 gl_lds per thread (oldest vmem ops)
    stage_tile(Vl, Vbase + kb, 2048, wave, lane);
    stage_tile(Vl + 128 * 64, Vbase + (size_t)128 * 2048 + kb, 2048, wave, lane);
    __builtin_amdgcn_sched_barrier(0);
    // phase 1b: consume sregs, issue next S loads (wrapped on last iter so
    // vmem counts stay uniform; wrapped data is never used)
    float e[16] = {s0.x, s0.y, s0.z, s0.w, s1.x, s1.y, s1.z, s1.w,
                   s2.x, s2.y, s2.z, s2.w, s3.x, s3.y, s3.z, s3.w};
    const int kn = (kb + 64) & 2047;
    s0 = *(const float4*)&srow[kn + cq * 16];
    s1 = *(const float4*)&srow[kn + cq * 16 + 4];
    s2 = *(const float4*)&srow[kn + cq * 16 + 8];
    s3 = *(const float4*)&srow[kn + cq * 16 + 12];
    __builtin_amdgcn_sched_barrier(0);
    // phase 1c: exp + swizzled P writes  (v_exp_f32 computes 2^x)
    #pragma unroll
    for (int g2 = 0; g2 < 2; ++g2) {
      f16x8 p;
      #pragma unroll
      for (int j = 0; j < 8; ++j) {
        const float ev =
            __builtin_amdgcn_exp2f(fmaf(e[g2 * 8 + j], LOG2E, -mls));
        l_part += ev;
        p[j] = (f16_t)ev;
      }
      const int slot = cq * 2 + g2;
      *(f16x8*)&P[qs * 64 + ((slot ^ (qs & 7)) << 3)] = p;
    }
    // (B) staging barrier: drain the 8 V gl_lds + P ds_writes; leave the
    // 4 S loads in flight across the MFMA phase.
    asm volatile("s_waitcnt vmcnt(4) lgkmcnt(0)\n\ts_barrier" ::: "memory");
    __builtin_amdgcn_sched_barrier(0);
    // phase 2: MFMA
    #pragma unroll
    for (int ks = 0; ks < 2; ++ks) {
      const int slot0 = ks * 4 + lg;
      f16x8 af[4], bf[4];
      #pragma unroll
      for (int g = 0; g < 4; ++g) {
        af[g] = lds_frag(P, g * 16 + l15, slot0);
        bf[g] = lds_frag(Vl, wave * 64 + g * 16 + l15, slot0);
      }
      #pragma unroll
      for (int i = 0; i < 4; ++i)
        #pragma unroll
        for (int j = 0; j < 4; ++j)
          acc[i][j] = mfma_h(af[i], bf[j], acc[i][j]);
    }
  }

  __syncthreads();                 // drains leftover wrapped S loads too
  lred[qs][cq] = l_part;
  __syncthreads();

  #pragma unroll
  for (int i = 0; i < 4; ++i)
    #pragma unroll
    for (int r = 0; r < 4; ++r) {
      const int ql = i * 16 + lg * 4 + r;
      const float l = lred[ql][0] + lred[ql][1] + lred[ql][2] + lred[ql][3];
      const float sc = 22.62741699796952f / l;   // sqrt(512)/l
      const size_t orow = ((size_t)bat * 2048 + qt * 64 + ql) * 512;
      #pragma unroll
      for (int j = 0; j < 4; ++j) {
        const int dv = dvh * 256 + wave * 64 + j * 16 + l15;
        out[orow + dv] = acc[i][j][r] * sc;
      }
    }
}

// ---------------------------------------------------------------------------
extern "C" void kernel_launch(void* const* d_in, const int* in_sizes, int n_in,
                              void* d_out, int out_size, void* d_ws, size_t ws_size,
                              hipStream_t stream) {
  const float* x  = (const float*)d_in[0];
  const float* Wq = (const float*)d_in[1];
  const float* bq = (const float*)d_in[2];
  const float* Wk = (const float*)d_in[3];
  const float* bk = (const float*)d_in[4];
  const float* Wv = (const float*)d_in[5];
  const float* bv = (const float*)d_in[6];
  float* out = (float*)d_out;

  char* ws = (char*)d_ws;
  f16_t* x16 = (f16_t*)(ws + 0);
  f16_t* Q   = (f16_t*)(ws + 16777216);
  f16_t* K   = (f16_t*)(ws + 33554432);
  f16_t* Vt  = (f16_t*)(ws + 50331648);
  float* S   = (float*)(ws + 67108864);
  f16_t* Wt  = (f16_t*)(ws + 201326592);
  unsigned int* mEnc = (unsigned int*)(ws + 202899456);

  (void)hipMemsetAsync(mEnc, 0, 65536, stream);  // encoded -inf sentinel
  k_conv_x<<<4096, 256, 0, stream>>>(x, x16);
  k_conv_w<<<dim3(8, 8, 3), 256, 0, stream>>>(Wq, Wk, Wv, Wt);
  k_proj<<<1536, 256, 0, stream>>>(x16, Wt, bq, bk, bv, Q, K, Vt);
  k_qk<<<2048, 256, 0, stream>>>(Q, K, S, mEnc);
  k_pv3<<<512, 256, 0, stream>>>(S, Vt, mEnc, out);
}